// Round 5
// baseline (1075.670 us; speedup 1.0000x reference)
//
#include <hip/hip_runtime.h>
#include <hip/hip_bf16.h>
#include <stdint.h>

typedef __bf16 bf16x8 __attribute__((ext_vector_type(8)));
typedef float f32x4 __attribute__((ext_vector_type(4)));

#define SOFTMAX_SCALE 0.08838834764831845f
#define LOG2E 1.44269504088896f

// load 8 contiguous elements as bf16x8, converting if the source is fp32
__device__ __forceinline__ bf16x8 load8_cvt(const __hip_bfloat16* p) {
  return *(const bf16x8*)p;
}
__device__ __forceinline__ bf16x8 load8_cvt(const float* p) {
  float4 a = *(const float4*)p;
  float4 b = *(const float4*)(p + 4);
  bf16x8 r;
  r[0] = (__bf16)a.x; r[1] = (__bf16)a.y; r[2] = (__bf16)a.z; r[3] = (__bf16)a.w;
  r[4] = (__bf16)b.x; r[5] = (__bf16)b.y; r[6] = (__bf16)b.z; r[7] = (__bf16)b.w;
  return r;
}

// async global->LDS DMA, 16B per lane. LDS dest is wave-uniform base + lane*16;
// swizzled layout achieved by pre-swizzling the per-lane GLOBAL source (rule #21).
__device__ __forceinline__ void gload_lds16(const __hip_bfloat16* g,
                                            __hip_bfloat16* l) {
  __builtin_amdgcn_global_load_lds(
      (__attribute__((address_space(1))) void*)(g),
      (__attribute__((address_space(3))) void*)(l), 16, 0, 0);
}

// ---------------------------------------------------------------------------
// fp32 -> bf16 bulk convert (grid-stride, 16B loads / 16B stores)
// ---------------------------------------------------------------------------
__global__ __launch_bounds__(256) void cvt_f32_bf16(
    const float* __restrict__ in, __hip_bfloat16* __restrict__ out, int n8)
{
  int i = blockIdx.x * blockDim.x + threadIdx.x;
  int stride = gridDim.x * blockDim.x;
  for (; i < n8; i += stride)
    *(bf16x8*)(out + (int64_t)i * 8) = load8_cvt(in + (int64_t)i * 8);
}

// ---------------------------------------------------------------------------
// GEMM core: C = A * B^T, tile 128x128, BK=64, 4 waves. (unchanged, verified)
// ---------------------------------------------------------------------------
template <typename TA, typename TB>
__device__ __forceinline__ void gemm_bt_loop(
    const TA* __restrict__ A,
    const TB* __restrict__ B,
    int K, int m0, int n0,
    __hip_bfloat16* As, __hip_bfloat16* Bs,
    f32x4 acc[4][4])
{
  const int t = threadIdx.x;
  const int w = t >> 6, lane = t & 63;
  const int wm = (w >> 1) * 64, wn = (w & 1) * 64;
  const int l16 = lane & 15, quad = lane >> 4;
  constexpr bool ASYNC = (sizeof(TA) == 2) && (sizeof(TB) == 2);

  for (int k0 = 0; k0 < K; k0 += 64) {
    if constexpr (ASYNC) {
      #pragma unroll
      for (int i = 0; i < 4; ++i) {
        int cb = (w * 4 + i) * 64;            // wave-uniform chunk base
        int idx = cb + lane;
        int row = idx >> 3;
        int chs = (idx & 7) ^ (row & 7);      // pre-swizzled source chunk
        gload_lds16((const __hip_bfloat16*)A + (int64_t)(m0 + row) * K + k0 + chs * 8,
                    As + cb * 8);
        gload_lds16((const __hip_bfloat16*)B + (int64_t)(n0 + row) * K + k0 + chs * 8,
                    Bs + cb * 8);
      }
    } else {
      #pragma unroll
      for (int i = 0; i < 4; ++i) {
        int idx = i * 256 + t;
        int row = idx >> 3, ch = idx & 7;
        int sw = (ch ^ (row & 7)) * 8;
        *(bf16x8*)(As + row * 64 + sw) =
            load8_cvt(A + (int64_t)(m0 + row) * K + k0 + ch * 8);
        *(bf16x8*)(Bs + row * 64 + sw) =
            load8_cvt(B + (int64_t)(n0 + row) * K + k0 + ch * 8);
      }
    }
    __syncthreads();
    #pragma unroll
    for (int ks = 0; ks < 2; ++ks) {
      bf16x8 af[4], bfr[4];
      #pragma unroll
      for (int mt = 0; mt < 4; ++mt) {
        int row = wm + mt * 16 + l16;
        int ch = ks * 4 + quad;
        af[mt] = *(const bf16x8*)(As + row * 64 + ((ch ^ (row & 7)) * 8));
      }
      #pragma unroll
      for (int nt = 0; nt < 4; ++nt) {
        int row = wn + nt * 16 + l16;
        int ch = ks * 4 + quad;
        bfr[nt] = *(const bf16x8*)(Bs + row * 64 + ((ch ^ (row & 7)) * 8));
      }
      #pragma unroll
      for (int mt = 0; mt < 4; ++mt)
        #pragma unroll
        for (int nt = 0; nt < 4; ++nt)
          acc[mt][nt] = __builtin_amdgcn_mfma_f32_16x16x32_bf16(
              af[mt], bfr[nt], acc[mt][nt], 0, 0, 0);
    }
    __syncthreads();
  }
}

// ---------------------------------------------------------------------------
// Kernel 1: QKV projection (unchanged, verified)
// ---------------------------------------------------------------------------
template <typename TA, typename TB>
__global__ __launch_bounds__(256) void qkv_gemm(
    const TA* __restrict__ A,
    const TB* __restrict__ W,
    __hip_bfloat16* __restrict__ qb,
    __hip_bfloat16* __restrict__ kb,
    __hip_bfloat16* __restrict__ vb)
{
  __shared__ __align__(16) __hip_bfloat16 As[128 * 64];
  __shared__ __align__(16) __hip_bfloat16 Bs[128 * 64];
  const f32x4 z4 = {0.f, 0.f, 0.f, 0.f};
  f32x4 acc[4][4];
  #pragma unroll
  for (int mt = 0; mt < 4; ++mt)
    #pragma unroll
    for (int nt = 0; nt < 4; ++nt) acc[mt][nt] = z4;

  const int K = 2048;
  const int n0 = blockIdx.x * 128, m0 = blockIdx.y * 128;
  gemm_bt_loop(A, W, K, m0, n0, As, Bs, acc);

  const int t = threadIdx.x;
  const int w = t >> 6, lane = t & 63;
  const int wm = (w >> 1) * 64, wn = (w & 1) * 64;
  const int l16 = lane & 15, quad = lane >> 4;
  __hip_bfloat16* bufs[3] = {qb, kb, vb};
  #pragma unroll
  for (int nt = 0; nt < 4; ++nt) {
    int gn = n0 + wn + nt * 16 + l16;
    int which = gn >> 11;          // 0=q 1=k 2=v
    int hc = gn & 2047;
    int head = hc >> 7, d = hc & 127;
    __hip_bfloat16* dst = bufs[which];
    #pragma unroll
    for (int mt = 0; mt < 4; ++mt) {
      #pragma unroll
      for (int r = 0; r < 4; ++r) {
        int gm = m0 + wm + mt * 16 + quad * 4 + r;
        int bb = gm >> 11, s = gm & 2047;
        float val = acc[mt][nt][r];
        val = fminf(8.f, fmaxf(-8.f, val));
        dst[(((int64_t)(bb * 16 + head) * 2048 + s) << 7) + d] =
            __float2bfloat16(val);
      }
    }
  }
}

// ---------------------------------------------------------------------------
// Kernel 2: V transpose per head (unchanged)
// ---------------------------------------------------------------------------
__global__ __launch_bounds__(256) void transpose_v(
    const __hip_bfloat16* __restrict__ V,
    __hip_bfloat16* __restrict__ Vt)
{
  __shared__ __hip_bfloat16 tile[64][68];
  const int bh = blockIdx.z;
  const int s0 = blockIdx.x * 64;
  const int d0 = blockIdx.y * 64;
  const int t = threadIdx.x;
  const int c = t & 63, rq = t >> 6;
  const __hip_bfloat16* Vp = V + (int64_t)bh * 2048 * 128;
  #pragma unroll
  for (int j = 0; j < 16; ++j) {
    int r = rq * 16 + j;
    tile[r][c] = Vp[(int64_t)(s0 + r) * 128 + d0 + c];
  }
  __syncthreads();
  __hip_bfloat16* Vo = Vt + (int64_t)bh * 128 * 2048;
  #pragma unroll
  for (int j = 0; j < 16; ++j) {
    int dd = rq * 16 + j;
    Vo[(int64_t)(d0 + dd) * 2048 + s0 + c] = tile[c][dd];
  }
}

// ---------------------------------------------------------------------------
// Kernel 3: flash attention, occupancy-first rewrite.
// KVBLK=64, SINGLE-buffered K/V via global_load_lds; LDS = 40 KB exactly
// (K 16 + V 16 + Ps 8) -> 4 blocks/CU = 16 waves/CU. No hand vmcnt / raw
// barriers: plain __syncthreads() (the GEMM-proven structure); the per-iter
// drain is hidden by the other 3 resident blocks (m114 overlap mechanism).
// Bias: 1-deep register prefetch, compiler-managed waits. All 1024 blocks
// co-resident; per-CU load decorrelated via qt-scramble (heuristic).
// ---------------------------------------------------------------------------
__device__ __forceinline__ void issue_kv(
    int te,
    const __hip_bfloat16* __restrict__ Kbase,
    const __hip_bfloat16* __restrict__ Vbase,
    __hip_bfloat16* Kn, __hip_bfloat16* Vn, int w, int lane)
{
  const __hip_bfloat16* Kp = Kbase + (int64_t)te * 64 * 128;
  const __hip_bfloat16* Vp = Vbase + te * 64;
  #pragma unroll
  for (int i = 0; i < 4; ++i) {
    int cb = (w * 4 + i) * 64;
    int idx = cb + lane;
    { int row = idx >> 4, chs = (idx & 15) ^ (row & 15);
      gload_lds16(Kp + row * 128 + chs * 8, Kn + cb * 8); }
    { int row = idx >> 3, chs = (idx & 7) ^ (row & 7);
      gload_lds16(Vp + (int64_t)row * 2048 + chs * 8, Vn + cb * 8); }
  }
}

__device__ __forceinline__ void load_bias16(
    const float* __restrict__ bp, int te, float (&b)[16])
{
  const int c = te * 64;
  #pragma unroll
  for (int nt = 0; nt < 4; ++nt)
    #pragma unroll
    for (int r = 0; r < 4; ++r)
      b[nt * 4 + r] = bp[(int64_t)r * 2048 + c + nt * 16];
}

__device__ __forceinline__ void attn_step(
    int kt, int ktmax, int q0,
    const __hip_bfloat16* __restrict__ Kbase,
    const __hip_bfloat16* __restrict__ Vbase,
    const float* __restrict__ bp,
    __hip_bfloat16* __restrict__ Ks,
    __hip_bfloat16* __restrict__ Vs,
    __hip_bfloat16* __restrict__ Ps,
    const bf16x8 (&qf)[4],
    float (&bcur)[16], float (&bnxt)[16],
    f32x4 (&O)[8], float (&m_r)[4], float (&l_r)[4],
    int w, int lane, int l16, int quad)
{
  // stage tile kt (single buffer; previous end-barrier guarantees readers done)
  issue_kv(kt, Kbase, Vbase, Ks, Vs, w, lane);
  __syncthreads();              // vmcnt(0)+lgkmcnt(0)+barrier: tile ready

  // ---- S = Q * K^T (16 q-rows x 64 keys per wave) ----
  const f32x4 z4 = {0.f, 0.f, 0.f, 0.f};
  f32x4 S[4];
  #pragma unroll
  for (int nt = 0; nt < 4; ++nt) S[nt] = z4;
  __builtin_amdgcn_s_setprio(1);
  #pragma unroll
  for (int ks = 0; ks < 4; ++ks) {
    int ch = ks * 4 + quad;
    bf16x8 kf[4];
    #pragma unroll
    for (int nt = 0; nt < 4; ++nt) {
      int row = nt * 16 + l16;
      kf[nt] = *(const bf16x8*)(Ks + row * 128 + ((ch ^ (row & 15)) * 8));
    }
    #pragma unroll
    for (int nt = 0; nt < 4; ++nt)
      S[nt] = __builtin_amdgcn_mfma_f32_16x16x32_bf16(
          qf[ks], kf[nt], S[nt], 0, 0, 0);
  }
  __builtin_amdgcn_s_setprio(0);

  // prefetch next-tile bias into registers; in flight through softmax+PV,
  // compiler inserts the wait before next step's use
  load_bias16(bp, (kt + 1 <= ktmax ? kt + 1 : ktmax), bnxt);

  // ---- scale + bias(regs) + causal mask ----
  const bool diag = (kt == ktmax);
  #pragma unroll
  for (int r = 0; r < 4; ++r) {
    int trow = w * 16 + quad * 4 + r;
    int gq = q0 + trow;
    float sv0 = S[0][r] * SOFTMAX_SCALE + bcur[r];
    float sv1 = S[1][r] * SOFTMAX_SCALE + bcur[4 + r];
    float sv2 = S[2][r] * SOFTMAX_SCALE + bcur[8 + r];
    float sv3 = S[3][r] * SOFTMAX_SCALE + bcur[12 + r];
    if (diag) {
      int colb = kt * 64 + l16;
      if (colb      > gq) sv0 = -3.0e38f;
      if (colb + 16 > gq) sv1 = -3.0e38f;
      if (colb + 32 > gq) sv2 = -3.0e38f;
      if (colb + 48 > gq) sv3 = -3.0e38f;
    }
    S[0][r] = sv0; S[1][r] = sv1; S[2][r] = sv2; S[3][r] = sv3;
  }

  // ---- online softmax (row stats across the 16 l16 lanes) ----
  #pragma unroll
  for (int r = 0; r < 4; ++r) {
    float rm = fmaxf(fmaxf(S[0][r], S[1][r]), fmaxf(S[2][r], S[3][r]));
    rm = fmaxf(rm, __shfl_xor(rm, 1, 64));
    rm = fmaxf(rm, __shfl_xor(rm, 2, 64));
    rm = fmaxf(rm, __shfl_xor(rm, 4, 64));
    rm = fmaxf(rm, __shfl_xor(rm, 8, 64));
    float mo = m_r[r];
    float mn = fmaxf(mo, rm);
    float alpha = exp2f((mo - mn) * LOG2E);
    float rs = 0.f;
    #pragma unroll
    for (int nt = 0; nt < 4; ++nt) {
      float pv = exp2f((S[nt][r] - mn) * LOG2E);
      S[nt][r] = pv;
      rs += pv;
    }
    rs += __shfl_xor(rs, 1, 64);
    rs += __shfl_xor(rs, 2, 64);
    rs += __shfl_xor(rs, 4, 64);
    rs += __shfl_xor(rs, 8, 64);
    m_r[r] = mn;
    l_r[r] = l_r[r] * alpha + rs;
    #pragma unroll
    for (int nt2 = 0; nt2 < 8; ++nt2) O[nt2][r] *= alpha;
  }

  // ---- P -> per-wave-private LDS rows (no barrier: only own wave reads) ----
  #pragma unroll
  for (int r = 0; r < 4; ++r) {
    int trow = w * 16 + quad * 4 + r;
    #pragma unroll
    for (int nt = 0; nt < 4; ++nt) {
      int col = nt * 16 + l16;
      Ps[trow * 64 + (((col >> 3) ^ (trow & 7)) << 3) + (col & 7)] =
          __float2bfloat16(S[nt][r]);
    }
  }

  // ---- O += P * V ----
  __builtin_amdgcn_s_setprio(1);
  #pragma unroll
  for (int ksp = 0; ksp < 2; ++ksp) {
    int ch = ksp * 4 + quad;
    int prow = w * 16 + l16;
    bf16x8 pf = *(const bf16x8*)(Ps + prow * 64 + ((ch ^ (prow & 7)) * 8));
    #pragma unroll
    for (int nt = 0; nt < 8; ++nt) {
      int row = nt * 16 + l16;
      bf16x8 vf = *(const bf16x8*)(Vs + row * 64 + ((ch ^ (row & 7)) * 8));
      O[nt] = __builtin_amdgcn_mfma_f32_16x16x32_bf16(pf, vf, O[nt], 0, 0, 0);
    }
  }
  __builtin_amdgcn_s_setprio(0);

  __syncthreads();              // all reads of tile kt done before overwrite
}

__global__ __launch_bounds__(256, 4) void attn_kernel(
    const __hip_bfloat16* __restrict__ Q,
    const __hip_bfloat16* __restrict__ Kg,
    const __hip_bfloat16* __restrict__ Vt,
    const float* __restrict__ bias,
    __hip_bfloat16* __restrict__ ctx)
{
  __shared__ __align__(16) __hip_bfloat16 Ks[64 * 128];   // 16 KB
  __shared__ __align__(16) __hip_bfloat16 Vs[128 * 64];   // 16 KB
  __shared__ __align__(16) __hip_bfloat16 Ps[64 * 64];    //  8 KB  -> 40 KB total

  const int t = threadIdx.x;
  const int w = t >> 6, lane = t & 63;
  const int l16 = lane & 15, quad = lane >> 4;

  const int y = blockIdx.y;
  const int h = y >> 1, b = y & 1;     // b=0/b=1 with same h adjacent (bias L2)
  const int bh = b * 16 + h;
  // qt scrambled so blocks co-resident on a CU (ids differing by 256 under
  // round-robin dispatch => same x, y+8k) get complementary work sizes.
  const int qt = (31 - (int)blockIdx.x + 8 * ((y >> 3) & 3)) & 31;
  const int q0 = qt * 64;
  const int ktmax = qt;                // 64-wide key tiles: 0..qt

  const __hip_bfloat16* Kbase = Kg + (int64_t)bh * 2048 * 128;
  const __hip_bfloat16* Vbase = Vt + (int64_t)bh * 128 * 2048;
  const float* bp = bias + (int64_t)h * 2048 * 2048
                    + (int64_t)(q0 + w * 16 + quad * 4) * 2048 + l16;

  // Q fragments: wave w covers q rows [q0 + w*16, +16)
  bf16x8 qf[4];
  {
    const __hip_bfloat16* Qp = Q + ((int64_t)bh * 2048 + q0 + w * 16) * 128;
    #pragma unroll
    for (int ks = 0; ks < 4; ++ks)
      qf[ks] = *(const bf16x8*)(Qp + l16 * 128 + ks * 32 + quad * 8);
  }

  const f32x4 z4 = {0.f, 0.f, 0.f, 0.f};
  f32x4 O[8];
  #pragma unroll
  for (int nt = 0; nt < 8; ++nt) O[nt] = z4;
  float m_r[4], l_r[4];
  #pragma unroll
  for (int r = 0; r < 4; ++r) { m_r[r] = -3.0e38f; l_r[r] = 0.f; }

  float bA[16], bB[16];
  load_bias16(bp, 0, bA);

  for (int kt = 0; kt <= ktmax; kt += 2) {
    attn_step(kt, ktmax, q0, Kbase, Vbase, bp, Ks, Vs, Ps, qf,
              bA, bB, O, m_r, l_r, w, lane, l16, quad);
    if (kt + 1 <= ktmax)
      attn_step(kt + 1, ktmax, q0, Kbase, Vbase, bp, Ks, Vs, Ps, qf,
                bB, bA, O, m_r, l_r, w, lane, l16, quad);
  }

  // epilogue: ctx[b*2048 + q][h*128 + d] = O / l   (bf16)
  #pragma unroll
  for (int r = 0; r < 4; ++r) {
    int trow = w * 16 + quad * 4 + r;
    int gm = b * 2048 + q0 + trow;
    float inv = 1.f / l_r[r];
    __hip_bfloat16* crow = ctx + (int64_t)gm * 2048 + h * 128;
    #pragma unroll
    for (int nt = 0; nt < 8; ++nt)
      crow[nt * 16 + l16] = __float2bfloat16(O[nt][r] * inv);
  }
}

// ---------------------------------------------------------------------------
// Kernel 4: output projection (unchanged)
// ---------------------------------------------------------------------------
template <typename TB>
__global__ __launch_bounds__(256) void out_gemm(
    const __hip_bfloat16* __restrict__ A,
    const TB* __restrict__ W,
    float* __restrict__ out)
{
  __shared__ __align__(16) __hip_bfloat16 As[128 * 64];
  __shared__ __align__(16) __hip_bfloat16 Bs[128 * 64];
  const f32x4 z4 = {0.f, 0.f, 0.f, 0.f};
  f32x4 acc[4][4];
  #pragma unroll
  for (int mt = 0; mt < 4; ++mt)
    #pragma unroll
    for (int nt = 0; nt < 4; ++nt) acc[mt][nt] = z4;

  const int K = 2048;
  const int n0 = blockIdx.x * 128, m0 = blockIdx.y * 128;
  gemm_bt_loop(A, W, K, m0, n0, As, Bs, acc);

  const int t = threadIdx.x;
  const int w = t >> 6, lane = t & 63;
  const int wm = (w >> 1) * 64, wn = (w & 1) * 64;
  const int l16 = lane & 15, quad = lane >> 4;
  #pragma unroll
  for (int mt = 0; mt < 4; ++mt) {
    #pragma unroll
    for (int r = 0; r < 4; ++r) {
      int gm = m0 + wm + mt * 16 + quad * 4 + r;
      #pragma unroll
      for (int nt = 0; nt < 4; ++nt) {
        int gn = n0 + wn + nt * 16 + l16;
        out[(int64_t)gm * 2048 + gn] = acc[mt][nt][r];
      }
    }
  }
}

// ---------------------------------------------------------------------------
extern "C" void kernel_launch(void* const* d_in, const int* in_sizes, int n_in,
                              void* d_out, int out_size, void* d_ws, size_t ws_size,
                              hipStream_t stream) {
  const float* hs   = (const float*)d_in[0];
  const float* bias = (const float*)d_in[1];
  // d_in[2] = attention_mask: pure causal, applied analytically; never read.
  const float* Wqkv = (const float*)d_in[3];
  const float* Wout = (const float*)d_in[4];
  float* out = (float*)d_out;

  __hip_bfloat16* ws = (__hip_bfloat16*)d_ws;
  const size_t SEG = (size_t)32 * 2048 * 128;   // 8,388,608 elements (16 MB)
  __hip_bfloat16* q   = ws;
  __hip_bfloat16* k   = ws + SEG;
  __hip_bfloat16* v   = ws + 2 * SEG;
  __hip_bfloat16* vt  = ws + 3 * SEG;
  __hip_bfloat16* ctx = ws + 2 * SEG;           // aliases v (dead after transpose)

  const size_t NW_QKV = (size_t)6144 * 2048;    // 12,582,912
  const size_t NW_OUT = (size_t)2048 * 2048;    //  4,194,304
  const size_t need_bytes = (4 * SEG + NW_QKV + SEG) * sizeof(__hip_bfloat16);

  if (ws_size >= need_bytes) {
    // fast path: pre-convert operands to bf16, halving GEMM staging bytes
    __hip_bfloat16* wqkvb = ws + 4 * SEG;
    __hip_bfloat16* hsb   = wqkvb + NW_QKV;
    __hip_bfloat16* woutb = wqkvb;              // aliases wqkvb (dead after qkv)
    cvt_f32_bf16<<<1024, 256, 0, stream>>>(hs, hsb, (int)(SEG / 8));
    cvt_f32_bf16<<<1024, 256, 0, stream>>>(Wqkv, wqkvb, (int)(NW_QKV / 8));
    qkv_gemm<__hip_bfloat16, __hip_bfloat16>
        <<<dim3(48, 32), 256, 0, stream>>>(hsb, wqkvb, q, k, v);
    transpose_v<<<dim3(32, 2, 32), 256, 0, stream>>>(v, vt);
    cvt_f32_bf16<<<1024, 256, 0, stream>>>(Wout, woutb, (int)(NW_OUT / 8));
    attn_kernel<<<dim3(32, 32), 256, 0, stream>>>(q, k, vt, bias, ctx);
    out_gemm<__hip_bfloat16><<<dim3(16, 32), 256, 0, stream>>>(ctx, woutb, out);
  } else {
    // fallback: fp32-direct staging (round-2 proven path)
    qkv_gemm<float, float><<<dim3(48, 32), 256, 0, stream>>>(hs, Wqkv, q, k, v);
    transpose_v<<<dim3(32, 2, 32), 256, 0, stream>>>(v, vt);
    attn_kernel<<<dim3(32, 32), 256, 0, stream>>>(q, k, vt, bias, ctx);
    out_gemm<float><<<dim3(16, 32), 256, 0, stream>>>(ctx, Wout, out);
  }
}

// Round 6
// 714.138 us; speedup vs baseline: 1.5062x; 1.5062x over previous
//
#include <hip/hip_runtime.h>
#include <hip/hip_bf16.h>
#include <stdint.h>

typedef __bf16 bf16x8 __attribute__((ext_vector_type(8)));
typedef float f32x4 __attribute__((ext_vector_type(4)));

#define SOFTMAX_SCALE 0.08838834764831845f
#define LOG2E 1.44269504088896f

// load 8 contiguous elements as bf16x8, converting if the source is fp32
__device__ __forceinline__ bf16x8 load8_cvt(const __hip_bfloat16* p) {
  return *(const bf16x8*)p;
}
__device__ __forceinline__ bf16x8 load8_cvt(const float* p) {
  float4 a = *(const float4*)p;
  float4 b = *(const float4*)(p + 4);
  bf16x8 r;
  r[0] = (__bf16)a.x; r[1] = (__bf16)a.y; r[2] = (__bf16)a.z; r[3] = (__bf16)a.w;
  r[4] = (__bf16)b.x; r[5] = (__bf16)b.y; r[6] = (__bf16)b.z; r[7] = (__bf16)b.w;
  return r;
}

// async global->LDS DMA, 16B per lane. LDS dest is wave-uniform base + lane*16;
// swizzled layout achieved by pre-swizzling the per-lane GLOBAL source (rule #21).
__device__ __forceinline__ void gload_lds16(const __hip_bfloat16* g,
                                            __hip_bfloat16* l) {
  __builtin_amdgcn_global_load_lds(
      (__attribute__((address_space(1))) void*)(g),
      (__attribute__((address_space(3))) void*)(l), 16, 0, 0);
}

// ---------------------------------------------------------------------------
// fp32 -> bf16 bulk convert (grid-stride, 16B loads / 16B stores)
// ---------------------------------------------------------------------------
__global__ __launch_bounds__(256) void cvt_f32_bf16(
    const float* __restrict__ in, __hip_bfloat16* __restrict__ out, int n8)
{
  int i = blockIdx.x * blockDim.x + threadIdx.x;
  int stride = gridDim.x * blockDim.x;
  for (; i < n8; i += stride)
    *(bf16x8*)(out + (int64_t)i * 8) = load8_cvt(in + (int64_t)i * 8);
}

// ---------------------------------------------------------------------------
// GEMM core: C = A * B^T, tile 128x128, BK=64, 4 waves. (unchanged, verified)
// ---------------------------------------------------------------------------
template <typename TA, typename TB>
__device__ __forceinline__ void gemm_bt_loop(
    const TA* __restrict__ A,
    const TB* __restrict__ B,
    int K, int m0, int n0,
    __hip_bfloat16* As, __hip_bfloat16* Bs,
    f32x4 acc[4][4])
{
  const int t = threadIdx.x;
  const int w = t >> 6, lane = t & 63;
  const int wm = (w >> 1) * 64, wn = (w & 1) * 64;
  const int l16 = lane & 15, quad = lane >> 4;
  constexpr bool ASYNC = (sizeof(TA) == 2) && (sizeof(TB) == 2);

  for (int k0 = 0; k0 < K; k0 += 64) {
    if constexpr (ASYNC) {
      #pragma unroll
      for (int i = 0; i < 4; ++i) {
        int cb = (w * 4 + i) * 64;            // wave-uniform chunk base
        int idx = cb + lane;
        int row = idx >> 3;
        int chs = (idx & 7) ^ (row & 7);      // pre-swizzled source chunk
        gload_lds16((const __hip_bfloat16*)A + (int64_t)(m0 + row) * K + k0 + chs * 8,
                    As + cb * 8);
        gload_lds16((const __hip_bfloat16*)B + (int64_t)(n0 + row) * K + k0 + chs * 8,
                    Bs + cb * 8);
      }
    } else {
      #pragma unroll
      for (int i = 0; i < 4; ++i) {
        int idx = i * 256 + t;
        int row = idx >> 3, ch = idx & 7;
        int sw = (ch ^ (row & 7)) * 8;
        *(bf16x8*)(As + row * 64 + sw) =
            load8_cvt(A + (int64_t)(m0 + row) * K + k0 + ch * 8);
        *(bf16x8*)(Bs + row * 64 + sw) =
            load8_cvt(B + (int64_t)(n0 + row) * K + k0 + ch * 8);
      }
    }
    __syncthreads();
    #pragma unroll
    for (int ks = 0; ks < 2; ++ks) {
      bf16x8 af[4], bfr[4];
      #pragma unroll
      for (int mt = 0; mt < 4; ++mt) {
        int row = wm + mt * 16 + l16;
        int ch = ks * 4 + quad;
        af[mt] = *(const bf16x8*)(As + row * 64 + ((ch ^ (row & 7)) * 8));
      }
      #pragma unroll
      for (int nt = 0; nt < 4; ++nt) {
        int row = wn + nt * 16 + l16;
        int ch = ks * 4 + quad;
        bfr[nt] = *(const bf16x8*)(Bs + row * 64 + ((ch ^ (row & 7)) * 8));
      }
      #pragma unroll
      for (int mt = 0; mt < 4; ++mt)
        #pragma unroll
        for (int nt = 0; nt < 4; ++nt)
          acc[mt][nt] = __builtin_amdgcn_mfma_f32_16x16x32_bf16(
              af[mt], bfr[nt], acc[mt][nt], 0, 0, 0);
    }
    __syncthreads();
  }
}

// ---------------------------------------------------------------------------
// Kernel 1: QKV projection (unchanged, verified)
// ---------------------------------------------------------------------------
template <typename TA, typename TB>
__global__ __launch_bounds__(256) void qkv_gemm(
    const TA* __restrict__ A,
    const TB* __restrict__ W,
    __hip_bfloat16* __restrict__ qb,
    __hip_bfloat16* __restrict__ kb,
    __hip_bfloat16* __restrict__ vb)
{
  __shared__ __align__(16) __hip_bfloat16 As[128 * 64];
  __shared__ __align__(16) __hip_bfloat16 Bs[128 * 64];
  const f32x4 z4 = {0.f, 0.f, 0.f, 0.f};
  f32x4 acc[4][4];
  #pragma unroll
  for (int mt = 0; mt < 4; ++mt)
    #pragma unroll
    for (int nt = 0; nt < 4; ++nt) acc[mt][nt] = z4;

  const int K = 2048;
  const int n0 = blockIdx.x * 128, m0 = blockIdx.y * 128;
  gemm_bt_loop(A, W, K, m0, n0, As, Bs, acc);

  const int t = threadIdx.x;
  const int w = t >> 6, lane = t & 63;
  const int wm = (w >> 1) * 64, wn = (w & 1) * 64;
  const int l16 = lane & 15, quad = lane >> 4;
  __hip_bfloat16* bufs[3] = {qb, kb, vb};
  #pragma unroll
  for (int nt = 0; nt < 4; ++nt) {
    int gn = n0 + wn + nt * 16 + l16;
    int which = gn >> 11;          // 0=q 1=k 2=v
    int hc = gn & 2047;
    int head = hc >> 7, d = hc & 127;
    __hip_bfloat16* dst = bufs[which];
    #pragma unroll
    for (int mt = 0; mt < 4; ++mt) {
      #pragma unroll
      for (int r = 0; r < 4; ++r) {
        int gm = m0 + wm + mt * 16 + quad * 4 + r;
        int bb = gm >> 11, s = gm & 2047;
        float val = acc[mt][nt][r];
        val = fminf(8.f, fmaxf(-8.f, val));
        dst[(((int64_t)(bb * 16 + head) * 2048 + s) << 7) + d] =
            __float2bfloat16(val);
      }
    }
  }
}

// ---------------------------------------------------------------------------
// Kernel 2: V transpose per head (unchanged)
// ---------------------------------------------------------------------------
__global__ __launch_bounds__(256) void transpose_v(
    const __hip_bfloat16* __restrict__ V,
    __hip_bfloat16* __restrict__ Vt)
{
  __shared__ __hip_bfloat16 tile[64][68];
  const int bh = blockIdx.z;
  const int s0 = blockIdx.x * 64;
  const int d0 = blockIdx.y * 64;
  const int t = threadIdx.x;
  const int c = t & 63, rq = t >> 6;
  const __hip_bfloat16* Vp = V + (int64_t)bh * 2048 * 128;
  #pragma unroll
  for (int j = 0; j < 16; ++j) {
    int r = rq * 16 + j;
    tile[r][c] = Vp[(int64_t)(s0 + r) * 128 + d0 + c];
  }
  __syncthreads();
  __hip_bfloat16* Vo = Vt + (int64_t)bh * 128 * 2048;
  #pragma unroll
  for (int j = 0; j < 16; ++j) {
    int dd = rq * 16 + j;
    Vo[(int64_t)(d0 + dd) * 2048 + s0 + c] = tile[c][dd];
  }
}

// ---------------------------------------------------------------------------
// Kernel 3: flash attention, occupancy-first (R5 structure, spill-free bounds).
// KVBLK=64, SINGLE-buffered K/V via global_load_lds; LDS = 40 KB exactly
// (K 16 + V 16 + Ps 8) -> 4 blocks/CU by LDS. __launch_bounds__(256,2): the
// R1/R2-proven setting (VGPR=100, zero spill); at VGPR<=128 the HW still
// schedules 4 waves/SIMD so the 4-block residency is preserved WITHOUT the
// (256,4) allocator squeeze that spilled to scratch (R5: VGPR=64, 423 MB
// scratch writes). Plain __syncthreads(); bias 1-deep register prefetch.
// ---------------------------------------------------------------------------
__device__ __forceinline__ void issue_kv(
    int te,
    const __hip_bfloat16* __restrict__ Kbase,
    const __hip_bfloat16* __restrict__ Vbase,
    __hip_bfloat16* Kn, __hip_bfloat16* Vn, int w, int lane)
{
  const __hip_bfloat16* Kp = Kbase + (int64_t)te * 64 * 128;
  const __hip_bfloat16* Vp = Vbase + te * 64;
  #pragma unroll
  for (int i = 0; i < 4; ++i) {
    int cb = (w * 4 + i) * 64;
    int idx = cb + lane;
    { int row = idx >> 4, chs = (idx & 15) ^ (row & 15);
      gload_lds16(Kp + row * 128 + chs * 8, Kn + cb * 8); }
    { int row = idx >> 3, chs = (idx & 7) ^ (row & 7);
      gload_lds16(Vp + (int64_t)row * 2048 + chs * 8, Vn + cb * 8); }
  }
}

__device__ __forceinline__ void load_bias16(
    const float* __restrict__ bp, int te, float (&b)[16])
{
  const int c = te * 64;
  #pragma unroll
  for (int nt = 0; nt < 4; ++nt)
    #pragma unroll
    for (int r = 0; r < 4; ++r)
      b[nt * 4 + r] = bp[(int64_t)r * 2048 + c + nt * 16];
}

__device__ __forceinline__ void attn_step(
    int kt, int ktmax, int q0,
    const __hip_bfloat16* __restrict__ Kbase,
    const __hip_bfloat16* __restrict__ Vbase,
    const float* __restrict__ bp,
    __hip_bfloat16* __restrict__ Ks,
    __hip_bfloat16* __restrict__ Vs,
    __hip_bfloat16* __restrict__ Ps,
    const bf16x8 (&qf)[4],
    float (&bcur)[16], float (&bnxt)[16],
    f32x4 (&O)[8], float (&m_r)[4], float (&l_r)[4],
    int w, int lane, int l16, int quad)
{
  // stage tile kt (single buffer; previous end-barrier guarantees readers done)
  issue_kv(kt, Kbase, Vbase, Ks, Vs, w, lane);
  __syncthreads();              // vmcnt(0)+lgkmcnt(0)+barrier: tile ready

  // ---- S = Q * K^T (16 q-rows x 64 keys per wave) ----
  const f32x4 z4 = {0.f, 0.f, 0.f, 0.f};
  f32x4 S[4];
  #pragma unroll
  for (int nt = 0; nt < 4; ++nt) S[nt] = z4;
  __builtin_amdgcn_s_setprio(1);
  #pragma unroll
  for (int ks = 0; ks < 4; ++ks) {
    int ch = ks * 4 + quad;
    bf16x8 kf[4];
    #pragma unroll
    for (int nt = 0; nt < 4; ++nt) {
      int row = nt * 16 + l16;
      kf[nt] = *(const bf16x8*)(Ks + row * 128 + ((ch ^ (row & 15)) * 8));
    }
    #pragma unroll
    for (int nt = 0; nt < 4; ++nt)
      S[nt] = __builtin_amdgcn_mfma_f32_16x16x32_bf16(
          qf[ks], kf[nt], S[nt], 0, 0, 0);
  }
  __builtin_amdgcn_s_setprio(0);

  // prefetch next-tile bias into registers; in flight through softmax+PV,
  // compiler inserts the wait before next step's use
  load_bias16(bp, (kt + 1 <= ktmax ? kt + 1 : ktmax), bnxt);

  // ---- scale + bias(regs) + causal mask ----
  const bool diag = (kt == ktmax);
  #pragma unroll
  for (int r = 0; r < 4; ++r) {
    int trow = w * 16 + quad * 4 + r;
    int gq = q0 + trow;
    float sv0 = S[0][r] * SOFTMAX_SCALE + bcur[r];
    float sv1 = S[1][r] * SOFTMAX_SCALE + bcur[4 + r];
    float sv2 = S[2][r] * SOFTMAX_SCALE + bcur[8 + r];
    float sv3 = S[3][r] * SOFTMAX_SCALE + bcur[12 + r];
    if (diag) {
      int colb = kt * 64 + l16;
      if (colb      > gq) sv0 = -3.0e38f;
      if (colb + 16 > gq) sv1 = -3.0e38f;
      if (colb + 32 > gq) sv2 = -3.0e38f;
      if (colb + 48 > gq) sv3 = -3.0e38f;
    }
    S[0][r] = sv0; S[1][r] = sv1; S[2][r] = sv2; S[3][r] = sv3;
  }

  // ---- online softmax (row stats across the 16 l16 lanes) ----
  #pragma unroll
  for (int r = 0; r < 4; ++r) {
    float rm = fmaxf(fmaxf(S[0][r], S[1][r]), fmaxf(S[2][r], S[3][r]));
    rm = fmaxf(rm, __shfl_xor(rm, 1, 64));
    rm = fmaxf(rm, __shfl_xor(rm, 2, 64));
    rm = fmaxf(rm, __shfl_xor(rm, 4, 64));
    rm = fmaxf(rm, __shfl_xor(rm, 8, 64));
    float mo = m_r[r];
    float mn = fmaxf(mo, rm);
    float alpha = exp2f((mo - mn) * LOG2E);
    float rs = 0.f;
    #pragma unroll
    for (int nt = 0; nt < 4; ++nt) {
      float pv = exp2f((S[nt][r] - mn) * LOG2E);
      S[nt][r] = pv;
      rs += pv;
    }
    rs += __shfl_xor(rs, 1, 64);
    rs += __shfl_xor(rs, 2, 64);
    rs += __shfl_xor(rs, 4, 64);
    rs += __shfl_xor(rs, 8, 64);
    m_r[r] = mn;
    l_r[r] = l_r[r] * alpha + rs;
    #pragma unroll
    for (int nt2 = 0; nt2 < 8; ++nt2) O[nt2][r] *= alpha;
  }

  // ---- P -> per-wave-private LDS rows (no barrier: only own wave reads) ----
  #pragma unroll
  for (int r = 0; r < 4; ++r) {
    int trow = w * 16 + quad * 4 + r;
    #pragma unroll
    for (int nt = 0; nt < 4; ++nt) {
      int col = nt * 16 + l16;
      Ps[trow * 64 + (((col >> 3) ^ (trow & 7)) << 3) + (col & 7)] =
          __float2bfloat16(S[nt][r]);
    }
  }

  // ---- O += P * V ----
  __builtin_amdgcn_s_setprio(1);
  #pragma unroll
  for (int ksp = 0; ksp < 2; ++ksp) {
    int ch = ksp * 4 + quad;
    int prow = w * 16 + l16;
    bf16x8 pf = *(const bf16x8*)(Ps + prow * 64 + ((ch ^ (prow & 7)) * 8));
    #pragma unroll
    for (int nt = 0; nt < 8; ++nt) {
      int row = nt * 16 + l16;
      bf16x8 vf = *(const bf16x8*)(Vs + row * 64 + ((ch ^ (row & 7)) * 8));
      O[nt] = __builtin_amdgcn_mfma_f32_16x16x32_bf16(pf, vf, O[nt], 0, 0, 0);
    }
  }
  __builtin_amdgcn_s_setprio(0);

  __syncthreads();              // all reads of tile kt done before overwrite
}

__global__ __launch_bounds__(256, 2) void attn_kernel(
    const __hip_bfloat16* __restrict__ Q,
    const __hip_bfloat16* __restrict__ Kg,
    const __hip_bfloat16* __restrict__ Vt,
    const float* __restrict__ bias,
    __hip_bfloat16* __restrict__ ctx)
{
  __shared__ __align__(16) __hip_bfloat16 Ks[64 * 128];   // 16 KB
  __shared__ __align__(16) __hip_bfloat16 Vs[128 * 64];   // 16 KB
  __shared__ __align__(16) __hip_bfloat16 Ps[64 * 64];    //  8 KB  -> 40 KB total

  const int t = threadIdx.x;
  const int w = t >> 6, lane = t & 63;
  const int l16 = lane & 15, quad = lane >> 4;

  const int y = blockIdx.y;
  const int h = y >> 1, b = y & 1;     // b=0/b=1 with same h adjacent (bias L2)
  const int bh = b * 16 + h;
  // qt scrambled so blocks co-resident on a CU (ids differing by 256 under
  // round-robin dispatch => same x, y+8k) get complementary work sizes.
  const int qt = (31 - (int)blockIdx.x + 8 * ((y >> 3) & 3)) & 31;
  const int q0 = qt * 64;
  const int ktmax = qt;                // 64-wide key tiles: 0..qt

  const __hip_bfloat16* Kbase = Kg + (int64_t)bh * 2048 * 128;
  const __hip_bfloat16* Vbase = Vt + (int64_t)bh * 128 * 2048;
  const float* bp = bias + (int64_t)h * 2048 * 2048
                    + (int64_t)(q0 + w * 16 + quad * 4) * 2048 + l16;

  // Q fragments: wave w covers q rows [q0 + w*16, +16)
  bf16x8 qf[4];
  {
    const __hip_bfloat16* Qp = Q + ((int64_t)bh * 2048 + q0 + w * 16) * 128;
    #pragma unroll
    for (int ks = 0; ks < 4; ++ks)
      qf[ks] = *(const bf16x8*)(Qp + l16 * 128 + ks * 32 + quad * 8);
  }

  const f32x4 z4 = {0.f, 0.f, 0.f, 0.f};
  f32x4 O[8];
  #pragma unroll
  for (int nt = 0; nt < 8; ++nt) O[nt] = z4;
  float m_r[4], l_r[4];
  #pragma unroll
  for (int r = 0; r < 4; ++r) { m_r[r] = -3.0e38f; l_r[r] = 0.f; }

  float bA[16], bB[16];
  load_bias16(bp, 0, bA);

  for (int kt = 0; kt <= ktmax; kt += 2) {
    attn_step(kt, ktmax, q0, Kbase, Vbase, bp, Ks, Vs, Ps, qf,
              bA, bB, O, m_r, l_r, w, lane, l16, quad);
    if (kt + 1 <= ktmax)
      attn_step(kt + 1, ktmax, q0, Kbase, Vbase, bp, Ks, Vs, Ps, qf,
                bB, bA, O, m_r, l_r, w, lane, l16, quad);
  }

  // epilogue: ctx[b*2048 + q][h*128 + d] = O / l   (bf16)
  #pragma unroll
  for (int r = 0; r < 4; ++r) {
    int trow = w * 16 + quad * 4 + r;
    int gm = b * 2048 + q0 + trow;
    float inv = 1.f / l_r[r];
    __hip_bfloat16* crow = ctx + (int64_t)gm * 2048 + h * 128;
    #pragma unroll
    for (int nt = 0; nt < 8; ++nt)
      crow[nt * 16 + l16] = __float2bfloat16(O[nt][r] * inv);
  }
}

// ---------------------------------------------------------------------------
// Kernel 4: output projection (unchanged)
// ---------------------------------------------------------------------------
template <typename TB>
__global__ __launch_bounds__(256) void out_gemm(
    const __hip_bfloat16* __restrict__ A,
    const TB* __restrict__ W,
    float* __restrict__ out)
{
  __shared__ __align__(16) __hip_bfloat16 As[128 * 64];
  __shared__ __align__(16) __hip_bfloat16 Bs[128 * 64];
  const f32x4 z4 = {0.f, 0.f, 0.f, 0.f};
  f32x4 acc[4][4];
  #pragma unroll
  for (int mt = 0; mt < 4; ++mt)
    #pragma unroll
    for (int nt = 0; nt < 4; ++nt) acc[mt][nt] = z4;

  const int K = 2048;
  const int n0 = blockIdx.x * 128, m0 = blockIdx.y * 128;
  gemm_bt_loop(A, W, K, m0, n0, As, Bs, acc);

  const int t = threadIdx.x;
  const int w = t >> 6, lane = t & 63;
  const int wm = (w >> 1) * 64, wn = (w & 1) * 64;
  const int l16 = lane & 15, quad = lane >> 4;
  #pragma unroll
  for (int mt = 0; mt < 4; ++mt) {
    #pragma unroll
    for (int r = 0; r < 4; ++r) {
      int gm = m0 + wm + mt * 16 + quad * 4 + r;
      #pragma unroll
      for (int nt = 0; nt < 4; ++nt) {
        int gn = n0 + wn + nt * 16 + l16;
        out[(int64_t)gm * 2048 + gn] = acc[mt][nt][r];
      }
    }
  }
}

// ---------------------------------------------------------------------------
extern "C" void kernel_launch(void* const* d_in, const int* in_sizes, int n_in,
                              void* d_out, int out_size, void* d_ws, size_t ws_size,
                              hipStream_t stream) {
  const float* hs   = (const float*)d_in[0];
  const float* bias = (const float*)d_in[1];
  // d_in[2] = attention_mask: pure causal, applied analytically; never read.
  const float* Wqkv = (const float*)d_in[3];
  const float* Wout = (const float*)d_in[4];
  float* out = (float*)d_out;

  __hip_bfloat16* ws = (__hip_bfloat16*)d_ws;
  const size_t SEG = (size_t)32 * 2048 * 128;   // 8,388,608 elements (16 MB)
  __hip_bfloat16* q   = ws;
  __hip_bfloat16* k   = ws + SEG;
  __hip_bfloat16* v   = ws + 2 * SEG;
  __hip_bfloat16* vt  = ws + 3 * SEG;
  __hip_bfloat16* ctx = ws + 2 * SEG;           // aliases v (dead after transpose)

  const size_t NW_QKV = (size_t)6144 * 2048;    // 12,582,912
  const size_t NW_OUT = (size_t)2048 * 2048;    //  4,194,304
  const size_t need_bytes = (4 * SEG + NW_QKV + SEG) * sizeof(__hip_bfloat16);

  if (ws_size >= need_bytes) {
    // fast path: pre-convert operands to bf16, halving GEMM staging bytes
    __hip_bfloat16* wqkvb = ws + 4 * SEG;
    __hip_bfloat16* hsb   = wqkvb + NW_QKV;
    __hip_bfloat16* woutb = wqkvb;              // aliases wqkvb (dead after qkv)
    cvt_f32_bf16<<<1024, 256, 0, stream>>>(hs, hsb, (int)(SEG / 8));
    cvt_f32_bf16<<<1024, 256, 0, stream>>>(Wqkv, wqkvb, (int)(NW_QKV / 8));
    qkv_gemm<__hip_bfloat16, __hip_bfloat16>
        <<<dim3(48, 32), 256, 0, stream>>>(hsb, wqkvb, q, k, v);
    transpose_v<<<dim3(32, 2, 32), 256, 0, stream>>>(v, vt);
    cvt_f32_bf16<<<1024, 256, 0, stream>>>(Wout, woutb, (int)(NW_OUT / 8));
    attn_kernel<<<dim3(32, 32), 256, 0, stream>>>(q, k, vt, bias, ctx);
    out_gemm<__hip_bfloat16><<<dim3(16, 32), 256, 0, stream>>>(ctx, woutb, out);
  } else {
    // fallback: fp32-direct staging (round-2 proven path)
    qkv_gemm<float, float><<<dim3(48, 32), 256, 0, stream>>>(hs, Wqkv, q, k, v);
    transpose_v<<<dim3(32, 2, 32), 256, 0, stream>>>(v, vt);
    attn_kernel<<<dim3(32, 32), 256, 0, stream>>>(q, k, vt, bias, ctx);
    out_gemm<float><<<dim3(16, 32), 256, 0, stream>>>(ctx, Wout, out);
  }
}

// Round 7
// 658.109 us; speedup vs baseline: 1.6345x; 1.0851x over previous
//
#include <hip/hip_runtime.h>
#include <hip/hip_bf16.h>
#include <stdint.h>

typedef __bf16 bf16x8 __attribute__((ext_vector_type(8)));
typedef float f32x4 __attribute__((ext_vector_type(4)));

#define SOFTMAX_SCALE 0.08838834764831845f
#define LOG2E 1.44269504088896f

// load 8 contiguous elements as bf16x8, converting if the source is fp32
__device__ __forceinline__ bf16x8 load8_cvt(const __hip_bfloat16* p) {
  return *(const bf16x8*)p;
}
__device__ __forceinline__ bf16x8 load8_cvt(const float* p) {
  float4 a = *(const float4*)p;
  float4 b = *(const float4*)(p + 4);
  bf16x8 r;
  r[0] = (__bf16)a.x; r[1] = (__bf16)a.y; r[2] = (__bf16)a.z; r[3] = (__bf16)a.w;
  r[4] = (__bf16)b.x; r[5] = (__bf16)b.y; r[6] = (__bf16)b.z; r[7] = (__bf16)b.w;
  return r;
}

// async global->LDS DMA, 16B per lane. LDS dest is wave-uniform base + lane*16;
// swizzled layout achieved by pre-swizzling the per-lane GLOBAL source (rule #21).
__device__ __forceinline__ void gload_lds16(const __hip_bfloat16* g,
                                            __hip_bfloat16* l) {
  __builtin_amdgcn_global_load_lds(
      (__attribute__((address_space(1))) void*)(g),
      (__attribute__((address_space(3))) void*)(l), 16, 0, 0);
}

// ---------------------------------------------------------------------------
// fp32 -> bf16 bulk convert (grid-stride, 16B loads / 16B stores)
// ---------------------------------------------------------------------------
__global__ __launch_bounds__(256) void cvt_f32_bf16(
    const float* __restrict__ in, __hip_bfloat16* __restrict__ out, int n8)
{
  int i = blockIdx.x * blockDim.x + threadIdx.x;
  int stride = gridDim.x * blockDim.x;
  for (; i < n8; i += stride)
    *(bf16x8*)(out + (int64_t)i * 8) = load8_cvt(in + (int64_t)i * 8);
}

// ---------------------------------------------------------------------------
// GEMM core: C = A * B^T, tile 128x128, BK=64, 4 waves. (unchanged, verified)
// ---------------------------------------------------------------------------
template <typename TA, typename TB>
__device__ __forceinline__ void gemm_bt_loop(
    const TA* __restrict__ A,
    const TB* __restrict__ B,
    int K, int m0, int n0,
    __hip_bfloat16* As, __hip_bfloat16* Bs,
    f32x4 acc[4][4])
{
  const int t = threadIdx.x;
  const int w = t >> 6, lane = t & 63;
  const int wm = (w >> 1) * 64, wn = (w & 1) * 64;
  const int l16 = lane & 15, quad = lane >> 4;
  constexpr bool ASYNC = (sizeof(TA) == 2) && (sizeof(TB) == 2);

  for (int k0 = 0; k0 < K; k0 += 64) {
    if constexpr (ASYNC) {
      #pragma unroll
      for (int i = 0; i < 4; ++i) {
        int cb = (w * 4 + i) * 64;            // wave-uniform chunk base
        int idx = cb + lane;
        int row = idx >> 3;
        int chs = (idx & 7) ^ (row & 7);      // pre-swizzled source chunk
        gload_lds16((const __hip_bfloat16*)A + (int64_t)(m0 + row) * K + k0 + chs * 8,
                    As + cb * 8);
        gload_lds16((const __hip_bfloat16*)B + (int64_t)(n0 + row) * K + k0 + chs * 8,
                    Bs + cb * 8);
      }
    } else {
      #pragma unroll
      for (int i = 0; i < 4; ++i) {
        int idx = i * 256 + t;
        int row = idx >> 3, ch = idx & 7;
        int sw = (ch ^ (row & 7)) * 8;
        *(bf16x8*)(As + row * 64 + sw) =
            load8_cvt(A + (int64_t)(m0 + row) * K + k0 + ch * 8);
        *(bf16x8*)(Bs + row * 64 + sw) =
            load8_cvt(B + (int64_t)(n0 + row) * K + k0 + ch * 8);
      }
    }
    __syncthreads();
    #pragma unroll
    for (int ks = 0; ks < 2; ++ks) {
      bf16x8 af[4], bfr[4];
      #pragma unroll
      for (int mt = 0; mt < 4; ++mt) {
        int row = wm + mt * 16 + l16;
        int ch = ks * 4 + quad;
        af[mt] = *(const bf16x8*)(As + row * 64 + ((ch ^ (row & 7)) * 8));
      }
      #pragma unroll
      for (int nt = 0; nt < 4; ++nt) {
        int row = wn + nt * 16 + l16;
        int ch = ks * 4 + quad;
        bfr[nt] = *(const bf16x8*)(Bs + row * 64 + ((ch ^ (row & 7)) * 8));
      }
      #pragma unroll
      for (int mt = 0; mt < 4; ++mt)
        #pragma unroll
        for (int nt = 0; nt < 4; ++nt)
          acc[mt][nt] = __builtin_amdgcn_mfma_f32_16x16x32_bf16(
              af[mt], bfr[nt], acc[mt][nt], 0, 0, 0);
    }
    __syncthreads();
  }
}

// ---------------------------------------------------------------------------
// Kernel 1: QKV projection (unchanged, verified)
// ---------------------------------------------------------------------------
template <typename TA, typename TB>
__global__ __launch_bounds__(256) void qkv_gemm(
    const TA* __restrict__ A,
    const TB* __restrict__ W,
    __hip_bfloat16* __restrict__ qb,
    __hip_bfloat16* __restrict__ kb,
    __hip_bfloat16* __restrict__ vb)
{
  __shared__ __align__(16) __hip_bfloat16 As[128 * 64];
  __shared__ __align__(16) __hip_bfloat16 Bs[128 * 64];
  const f32x4 z4 = {0.f, 0.f, 0.f, 0.f};
  f32x4 acc[4][4];
  #pragma unroll
  for (int mt = 0; mt < 4; ++mt)
    #pragma unroll
    for (int nt = 0; nt < 4; ++nt) acc[mt][nt] = z4;

  const int K = 2048;
  const int n0 = blockIdx.x * 128, m0 = blockIdx.y * 128;
  gemm_bt_loop(A, W, K, m0, n0, As, Bs, acc);

  const int t = threadIdx.x;
  const int w = t >> 6, lane = t & 63;
  const int wm = (w >> 1) * 64, wn = (w & 1) * 64;
  const int l16 = lane & 15, quad = lane >> 4;
  __hip_bfloat16* bufs[3] = {qb, kb, vb};
  #pragma unroll
  for (int nt = 0; nt < 4; ++nt) {
    int gn = n0 + wn + nt * 16 + l16;
    int which = gn >> 11;          // 0=q 1=k 2=v
    int hc = gn & 2047;
    int head = hc >> 7, d = hc & 127;
    __hip_bfloat16* dst = bufs[which];
    #pragma unroll
    for (int mt = 0; mt < 4; ++mt) {
      #pragma unroll
      for (int r = 0; r < 4; ++r) {
        int gm = m0 + wm + mt * 16 + quad * 4 + r;
        int bb = gm >> 11, s = gm & 2047;
        float val = acc[mt][nt][r];
        val = fminf(8.f, fmaxf(-8.f, val));
        dst[(((int64_t)(bb * 16 + head) * 2048 + s) << 7) + d] =
            __float2bfloat16(val);
      }
    }
  }
}

// ---------------------------------------------------------------------------
// Kernel 2: V transpose per head (unchanged)
// ---------------------------------------------------------------------------
__global__ __launch_bounds__(256) void transpose_v(
    const __hip_bfloat16* __restrict__ V,
    __hip_bfloat16* __restrict__ Vt)
{
  __shared__ __hip_bfloat16 tile[64][68];
  const int bh = blockIdx.z;
  const int s0 = blockIdx.x * 64;
  const int d0 = blockIdx.y * 64;
  const int t = threadIdx.x;
  const int c = t & 63, rq = t >> 6;
  const __hip_bfloat16* Vp = V + (int64_t)bh * 2048 * 128;
  #pragma unroll
  for (int j = 0; j < 16; ++j) {
    int r = rq * 16 + j;
    tile[r][c] = Vp[(int64_t)(s0 + r) * 128 + d0 + c];
  }
  __syncthreads();
  __hip_bfloat16* Vo = Vt + (int64_t)bh * 128 * 2048;
  #pragma unroll
  for (int j = 0; j < 16; ++j) {
    int dd = rq * 16 + j;
    Vo[(int64_t)(d0 + dd) * 2048 + s0 + c] = tile[c][dd];
  }
}

// ---------------------------------------------------------------------------
// Kernel 3: flash attention — q-tile-PAIR blocks (512 thr / 8 waves).
// Each block processes q-tiles {2p, 2p+1} sharing one K/V staging stream:
// waves 0-3 -> tile 2p, waves 4-7 -> tile 2p+1. Halves the number of staging
// events + barrier drains per unit of MFMA work (528 -> 272 per bh) and
// GUARANTEES 8 waves/CU co-resident (a workgroup's waves must all fit).
// ktmax = 2p+1 (odd) -> loop is a clean kt,kt+1 double step, no ragged tail;
// the lo tile's final (fully-masked) key-tile contributes P=0, alpha=1.
// Grid: 256 blocks, x=0..7 -> passes {15-x, x} = uniform 34 iterations/block.
// LDS: K 16 + V 16 + Ps 2x8 = 48 KB. Plain __syncthreads(); bias 1-deep
// register prefetch (R6-proven per-wave logic, byte-identical math).
// ---------------------------------------------------------------------------
__device__ __forceinline__ void issue_kv8(
    int te,
    const __hip_bfloat16* __restrict__ Kbase,
    const __hip_bfloat16* __restrict__ Vbase,
    __hip_bfloat16* Ks, __hip_bfloat16* Vs, int w, int lane)
{
  const __hip_bfloat16* Kp = Kbase + (int64_t)te * 64 * 128;
  const __hip_bfloat16* Vp = Vbase + te * 64;
  #pragma unroll
  for (int i = 0; i < 2; ++i) {
    int cb = (w * 2 + i) * 64;         // 16 wave-chunks cover 1024 chunks
    int idx = cb + lane;
    { int row = idx >> 4, chs = (idx & 15) ^ (row & 15);
      gload_lds16(Kp + row * 128 + chs * 8, Ks + cb * 8); }
    { int row = idx >> 3, chs = (idx & 7) ^ (row & 7);
      gload_lds16(Vp + (int64_t)row * 2048 + chs * 8, Vs + cb * 8); }
  }
}

__device__ __forceinline__ void load_bias16(
    const float* __restrict__ bp, int te, float (&b)[16])
{
  const int c = te * 64;
  #pragma unroll
  for (int nt = 0; nt < 4; ++nt)
    #pragma unroll
    for (int r = 0; r < 4; ++r)
      b[nt * 4 + r] = bp[(int64_t)r * 2048 + c + nt * 16];
}

__device__ __forceinline__ void attn_step(
    int kt, int ktmax, int q0w,
    const __hip_bfloat16* __restrict__ Kbase,
    const __hip_bfloat16* __restrict__ Vbase,
    const float* __restrict__ bp,
    __hip_bfloat16* __restrict__ Ks,
    __hip_bfloat16* __restrict__ Vs,
    __hip_bfloat16* __restrict__ Psh,   // this half's 64x64 P buffer
    const bf16x8 (&qf)[4],
    float (&bcur)[16], float (&bnxt)[16],
    f32x4 (&O)[8], float (&m_r)[4], float (&l_r)[4],
    int w, int w4, int lane, int l16, int quad)
{
  // stage tile kt (single buffer; previous end-barrier guarantees readers done)
  issue_kv8(kt, Kbase, Vbase, Ks, Vs, w, lane);
  __syncthreads();              // vmcnt(0)+lgkmcnt(0)+barrier: tile ready

  // ---- S = Q * K^T (16 q-rows x 64 keys per wave) ----
  const f32x4 z4 = {0.f, 0.f, 0.f, 0.f};
  f32x4 S[4];
  #pragma unroll
  for (int nt = 0; nt < 4; ++nt) S[nt] = z4;
  __builtin_amdgcn_s_setprio(1);
  #pragma unroll
  for (int ks = 0; ks < 4; ++ks) {
    int ch = ks * 4 + quad;
    bf16x8 kf[4];
    #pragma unroll
    for (int nt = 0; nt < 4; ++nt) {
      int row = nt * 16 + l16;
      kf[nt] = *(const bf16x8*)(Ks + row * 128 + ((ch ^ (row & 15)) * 8));
    }
    #pragma unroll
    for (int nt = 0; nt < 4; ++nt)
      S[nt] = __builtin_amdgcn_mfma_f32_16x16x32_bf16(
          qf[ks], kf[nt], S[nt], 0, 0, 0);
  }
  __builtin_amdgcn_s_setprio(0);

  // prefetch next-tile bias into registers (compiler-managed waits)
  load_bias16(bp, (kt + 1 <= ktmax ? kt + 1 : ktmax), bnxt);

  // ---- scale + bias(regs) + causal mask (unconditional: col>gq masks; for
  //      earlier tiles the condition is statically false, for the lo half's
  //      final tile it masks everything -> P=0, alpha=1) ----
  #pragma unroll
  for (int r = 0; r < 4; ++r) {
    int gq = q0w + quad * 4 + r;
    int colb = kt * 64 + l16;
    float sv0 = S[0][r] * SOFTMAX_SCALE + bcur[r];
    float sv1 = S[1][r] * SOFTMAX_SCALE + bcur[4 + r];
    float sv2 = S[2][r] * SOFTMAX_SCALE + bcur[8 + r];
    float sv3 = S[3][r] * SOFTMAX_SCALE + bcur[12 + r];
    if (colb      > gq) sv0 = -3.0e38f;
    if (colb + 16 > gq) sv1 = -3.0e38f;
    if (colb + 32 > gq) sv2 = -3.0e38f;
    if (colb + 48 > gq) sv3 = -3.0e38f;
    S[0][r] = sv0; S[1][r] = sv1; S[2][r] = sv2; S[3][r] = sv3;
  }

  // ---- online softmax (row stats across the 16 l16 lanes) ----
  #pragma unroll
  for (int r = 0; r < 4; ++r) {
    float rm = fmaxf(fmaxf(S[0][r], S[1][r]), fmaxf(S[2][r], S[3][r]));
    rm = fmaxf(rm, __shfl_xor(rm, 1, 64));
    rm = fmaxf(rm, __shfl_xor(rm, 2, 64));
    rm = fmaxf(rm, __shfl_xor(rm, 4, 64));
    rm = fmaxf(rm, __shfl_xor(rm, 8, 64));
    float mo = m_r[r];
    float mn = fmaxf(mo, rm);
    float alpha = exp2f((mo - mn) * LOG2E);
    float rs = 0.f;
    #pragma unroll
    for (int nt = 0; nt < 4; ++nt) {
      float pv = exp2f((S[nt][r] - mn) * LOG2E);
      S[nt][r] = pv;
      rs += pv;
    }
    rs += __shfl_xor(rs, 1, 64);
    rs += __shfl_xor(rs, 2, 64);
    rs += __shfl_xor(rs, 4, 64);
    rs += __shfl_xor(rs, 8, 64);
    m_r[r] = mn;
    l_r[r] = l_r[r] * alpha + rs;
    #pragma unroll
    for (int nt2 = 0; nt2 < 8; ++nt2) O[nt2][r] *= alpha;
  }

  // ---- P -> per-wave-private LDS rows (no barrier: only own wave reads) ----
  #pragma unroll
  for (int r = 0; r < 4; ++r) {
    int trow = w4 * 16 + quad * 4 + r;
    #pragma unroll
    for (int nt = 0; nt < 4; ++nt) {
      int col = nt * 16 + l16;
      Psh[trow * 64 + (((col >> 3) ^ (trow & 7)) << 3) + (col & 7)] =
          __float2bfloat16(S[nt][r]);
    }
  }

  // ---- O += P * V ----
  __builtin_amdgcn_s_setprio(1);
  #pragma unroll
  for (int ksp = 0; ksp < 2; ++ksp) {
    int ch = ksp * 4 + quad;
    int prow = w4 * 16 + l16;
    bf16x8 pf = *(const bf16x8*)(Psh + prow * 64 + ((ch ^ (prow & 7)) * 8));
    #pragma unroll
    for (int nt = 0; nt < 8; ++nt) {
      int row = nt * 16 + l16;
      bf16x8 vf = *(const bf16x8*)(Vs + row * 64 + ((ch ^ (row & 7)) * 8));
      O[nt] = __builtin_amdgcn_mfma_f32_16x16x32_bf16(pf, vf, O[nt], 0, 0, 0);
    }
  }
  __builtin_amdgcn_s_setprio(0);

  __syncthreads();              // all reads of tile kt done before overwrite
}

__device__ __forceinline__ void attn_pass(
    int pair, int b, int h,
    const __hip_bfloat16* __restrict__ Q,
    const __hip_bfloat16* __restrict__ Kbase,
    const __hip_bfloat16* __restrict__ Vbase,
    const float* __restrict__ Bb,
    __hip_bfloat16* __restrict__ ctx,
    __hip_bfloat16* Ks, __hip_bfloat16* Vs, __hip_bfloat16* Psh,
    int w, int w4, int lane, int l16, int quad)
{
  const int bh = b * 16 + h;
  const int ktmax = 2 * pair + 1;                 // odd -> clean double-step
  const int q0w = (2 * pair + (w >> 2)) * 64 + w4 * 16;  // wave's 16-row base

  const float* bp = Bb + (int64_t)(q0w + quad * 4) * 2048 + l16;

  // Q fragments for this wave's 16 rows
  bf16x8 qf[4];
  {
    const __hip_bfloat16* Qp = Q + ((int64_t)bh * 2048 + q0w) * 128;
    #pragma unroll
    for (int ks = 0; ks < 4; ++ks)
      qf[ks] = *(const bf16x8*)(Qp + l16 * 128 + ks * 32 + quad * 8);
  }

  const f32x4 z4 = {0.f, 0.f, 0.f, 0.f};
  f32x4 O[8];
  #pragma unroll
  for (int nt = 0; nt < 8; ++nt) O[nt] = z4;
  float m_r[4], l_r[4];
  #pragma unroll
  for (int r = 0; r < 4; ++r) { m_r[r] = -3.0e38f; l_r[r] = 0.f; }

  float bA[16], bB[16];
  load_bias16(bp, 0, bA);

  for (int kt = 0; kt < ktmax; kt += 2) {
    attn_step(kt, ktmax, q0w, Kbase, Vbase, bp, Ks, Vs, Psh, qf,
              bA, bB, O, m_r, l_r, w, w4, lane, l16, quad);
    attn_step(kt + 1, ktmax, q0w, Kbase, Vbase, bp, Ks, Vs, Psh, qf,
              bB, bA, O, m_r, l_r, w, w4, lane, l16, quad);
  }

  // epilogue: ctx[b*2048 + q][h*128 + d] = O / l   (bf16)
  #pragma unroll
  for (int r = 0; r < 4; ++r) {
    int gm = b * 2048 + q0w + quad * 4 + r;
    float inv = 1.f / l_r[r];
    __hip_bfloat16* crow = ctx + (int64_t)gm * 2048 + h * 128;
    #pragma unroll
    for (int nt = 0; nt < 8; ++nt)
      crow[nt * 16 + l16] = __float2bfloat16(O[nt][r] * inv);
  }
}

__global__ __launch_bounds__(512, 2) void attn_kernel(
    const __hip_bfloat16* __restrict__ Q,
    const __hip_bfloat16* __restrict__ Kg,
    const __hip_bfloat16* __restrict__ Vt,
    const float* __restrict__ bias,
    __hip_bfloat16* __restrict__ ctx)
{
  __shared__ __align__(16) __hip_bfloat16 Ks[64 * 128];     // 16 KB
  __shared__ __align__(16) __hip_bfloat16 Vs[128 * 64];     // 16 KB
  __shared__ __align__(16) __hip_bfloat16 Ps[2 * 64 * 64];  // 16 KB -> 48 KB

  const int t = threadIdx.x;
  const int w = t >> 6, lane = t & 63;
  const int w4 = w & 3;
  const int l16 = lane & 15, quad = lane >> 4;

  const int y = blockIdx.y;
  const int h = y >> 1, b = y & 1;     // b=0/b=1 with same h adjacent (bias L2)
  const int bh = b * 16 + h;
  const int x = blockIdx.x;            // 0..7

  const __hip_bfloat16* Kbase = Kg + (int64_t)bh * 2048 * 128;
  const __hip_bfloat16* Vbase = Vt + (int64_t)bh * 128 * 2048;
  const float* Bb = bias + (int64_t)h * 2048 * 2048;
  __hip_bfloat16* Psh = Ps + (w >> 2) * 64 * 64;

  // pairs (15-x) then (x): uniform 34 staging iterations per block
  attn_pass(15 - x, b, h, Q, Kbase, Vbase, Bb, ctx, Ks, Vs, Psh,
            w, w4, lane, l16, quad);
  attn_pass(x, b, h, Q, Kbase, Vbase, Bb, ctx, Ks, Vs, Psh,
            w, w4, lane, l16, quad);
}

// ---------------------------------------------------------------------------
// Kernel 4: output projection (unchanged)
// ---------------------------------------------------------------------------
template <typename TB>
__global__ __launch_bounds__(256) void out_gemm(
    const __hip_bfloat16* __restrict__ A,
    const TB* __restrict__ W,
    float* __restrict__ out)
{
  __shared__ __align__(16) __hip_bfloat16 As[128 * 64];
  __shared__ __align__(16) __hip_bfloat16 Bs[128 * 64];
  const f32x4 z4 = {0.f, 0.f, 0.f, 0.f};
  f32x4 acc[4][4];
  #pragma unroll
  for (int mt = 0; mt < 4; ++mt)
    #pragma unroll
    for (int nt = 0; nt < 4; ++nt) acc[mt][nt] = z4;

  const int K = 2048;
  const int n0 = blockIdx.x * 128, m0 = blockIdx.y * 128;
  gemm_bt_loop(A, W, K, m0, n0, As, Bs, acc);

  const int t = threadIdx.x;
  const int w = t >> 6, lane = t & 63;
  const int wm = (w >> 1) * 64, wn = (w & 1) * 64;
  const int l16 = lane & 15, quad = lane >> 4;
  #pragma unroll
  for (int mt = 0; mt < 4; ++mt) {
    #pragma unroll
    for (int r = 0; r < 4; ++r) {
      int gm = m0 + wm + mt * 16 + quad * 4 + r;
      #pragma unroll
      for (int nt = 0; nt < 4; ++nt) {
        int gn = n0 + wn + nt * 16 + l16;
        out[(int64_t)gm * 2048 + gn] = acc[mt][nt][r];
      }
    }
  }
}

// ---------------------------------------------------------------------------
extern "C" void kernel_launch(void* const* d_in, const int* in_sizes, int n_in,
                              void* d_out, int out_size, void* d_ws, size_t ws_size,
                              hipStream_t stream) {
  const float* hs   = (const float*)d_in[0];
  const float* bias = (const float*)d_in[1];
  // d_in[2] = attention_mask: pure causal, applied analytically; never read.
  const float* Wqkv = (const float*)d_in[3];
  const float* Wout = (const float*)d_in[4];
  float* out = (float*)d_out;

  __hip_bfloat16* ws = (__hip_bfloat16*)d_ws;
  const size_t SEG = (size_t)32 * 2048 * 128;   // 8,388,608 elements (16 MB)
  __hip_bfloat16* q   = ws;
  __hip_bfloat16* k   = ws + SEG;
  __hip_bfloat16* v   = ws + 2 * SEG;
  __hip_bfloat16* vt  = ws + 3 * SEG;
  __hip_bfloat16* ctx = ws + 2 * SEG;           // aliases v (dead after transpose)

  const size_t NW_QKV = (size_t)6144 * 2048;    // 12,582,912
  const size_t NW_OUT = (size_t)2048 * 2048;    //  4,194,304
  const size_t need_bytes = (4 * SEG + NW_QKV + SEG) * sizeof(__hip_bfloat16);

  if (ws_size >= need_bytes) {
    // fast path: pre-convert operands to bf16, halving GEMM staging bytes
    __hip_bfloat16* wqkvb = ws + 4 * SEG;
    __hip_bfloat16* hsb   = wqkvb + NW_QKV;
    __hip_bfloat16* woutb = wqkvb;              // aliases wqkvb (dead after qkv)
    cvt_f32_bf16<<<1024, 256, 0, stream>>>(hs, hsb, (int)(SEG / 8));
    cvt_f32_bf16<<<1024, 256, 0, stream>>>(Wqkv, wqkvb, (int)(NW_QKV / 8));
    qkv_gemm<__hip_bfloat16, __hip_bfloat16>
        <<<dim3(48, 32), 256, 0, stream>>>(hsb, wqkvb, q, k, v);
    transpose_v<<<dim3(32, 2, 32), 256, 0, stream>>>(v, vt);
    cvt_f32_bf16<<<1024, 256, 0, stream>>>(Wout, woutb, (int)(NW_OUT / 8));
    attn_kernel<<<dim3(8, 32), 512, 0, stream>>>(q, k, vt, bias, ctx);
    out_gemm<__hip_bfloat16><<<dim3(16, 32), 256, 0, stream>>>(ctx, woutb, out);
  } else {
    // fallback: fp32-direct staging (round-2 proven path)
    qkv_gemm<float, float><<<dim3(48, 32), 256, 0, stream>>>(hs, Wqkv, q, k, v);
    transpose_v<<<dim3(32, 2, 32), 256, 0, stream>>>(v, vt);
    attn_kernel<<<dim3(8, 32), 512, 0, stream>>>(q, k, vt, bias, ctx);
    out_gemm<float><<<dim3(16, 32), 256, 0, stream>>>(ctx, Wout, out);
  }
}